// Round 4
// baseline (108.139 us; speedup 1.0000x reference)
//
#include <hip/hip_runtime.h>
#include <math.h>

#define TOTAL 200      // distance bins (STOP/DELTA)
#define TB    32       // tile columns
#define BLK   256      // threads per block = tile rows
#define NW    4        // waves per block
#define GRID  2048     // persistent blocks: 8/CU x 256 CU
#define NR    16       // replicated global histograms
#define RATIO (BLK/TB) // 8: cbMin(rb) = RATIO*rb for self-pair triangles

// ---------------------------------------------------------------------------
// prep: scale positions by real_size, pack float4{x,y,z,|p|^2}; zero the NR
// replicated global histograms. (verbatim from the verified round-0 kernel)
// ---------------------------------------------------------------------------
__global__ void rdf_prep(const float* __restrict__ p0, const float* __restrict__ p1,
                         const float* __restrict__ rs,
                         float4* __restrict__ b0, float4* __restrict__ b1,
                         unsigned int* __restrict__ ghist, int n0, int n1)
{
    const float sx = rs[0], sy = rs[1], sz = rs[2];
    int t = blockIdx.x * blockDim.x + threadIdx.x;
    if (t < n0) {
        float x = p0[t*3+0]*sx, y = p0[t*3+1]*sy, z = p0[t*3+2]*sz;
        b0[t] = make_float4(x, y, z, x*x + y*y + z*z);
    } else if (t < n0 + n1) {
        int u = t - n0;
        float x = p1[u*3+0]*sx, y = p1[u*3+1]*sy, z = p1[u*3+2]*sz;
        b1[u] = make_float4(x, y, z, x*x + y*y + z*z);
    }
    if (t < NR * 3 * TOTAL) ghist[t] = 0;   // 9600 words <= grid threads
}

// ---------------------------------------------------------------------------
// inner pair loop, round-4: B via v_readlane broadcast from lane-private regs.
//
// WHY: rounds 0/1/3 delivered B via SMEM / VMEM-asm / LDS ds_read — all three
// pinned at 47-52us, VALUBusy ~50%, identical bank-conflict count. Common
// wall: every B use needed a waitcnt (lgkmcnt drags the in-order ds_add
// queue; vmcnt exposed full VMEM latency). Here the j-loop has ZERO waitcnt:
// readlane is a VALU op, j is an unroll-time literal, and the exec-masked
// ds_add needs no wait. Arithmetic tree is bit-identical (readlane moves
// bits) -> absmax must stay 0.0.
// ---------------------------------------------------------------------------
template<bool DIAG>
__device__ __forceinline__ void pair_loop(float4 bp,
                                          float ax, float ay, float az, float a2,
                                          unsigned int* __restrict__ mylh, int ofs)
{
    const int bx = __float_as_int(bp.x), by = __float_as_int(bp.y),
              bz = __float_as_int(bp.z), bw = __float_as_int(bp.w);
    #pragma unroll
    for (int j = 0; j < TB; ++j) {
        float qx = __int_as_float(__builtin_amdgcn_readlane(bx, j));
        float qy = __int_as_float(__builtin_amdgcn_readlane(by, j));
        float qz = __int_as_float(__builtin_amdgcn_readlane(bz, j));
        float qw = __int_as_float(__builtin_amdgcn_readlane(bw, j));
        float dot = ax*qx + ay*qy + az*qz;
        float d2  = (a2 + qw) - 2.0f*dot;                     // reference identity
        float v   = __builtin_amdgcn_sqrtf(fmaxf(d2, 0.0f)) * 20.0f;
        bool ok   = (v < 200.0f);
        if (DIAG) ok = ok && (j > ofs);
        if (ok) atomicAdd(&mylh[(int)v], 1u);
    }
}

// ---------------------------------------------------------------------------
// persistent pair-histogram kernel — round-0 structure verbatim (3-type
// [wave][parity]-private LDS hists, contiguous tile chunks, single flush).
// Only change: per tile, lane l holds B[colBase + (l&31)] in registers
// (per-lane VMEM load, 1 vmcnt wait per 32 j's); j-loop broadcasts via
// readlane.
// ---------------------------------------------------------------------------
__global__ __launch_bounds__(BLK) void rdf_hist(
    const float4* __restrict__ b0, const float4* __restrict__ b1,
    unsigned int* __restrict__ ghist,
    int n0, int n1, int T0, int T01, int Ttot,
    int cb0, int cb1, int rows0, int rows1)
{
    __shared__ unsigned int lh[3][NW][2][TOTAL];   // 19.2 KB -> 8 blocks/CU

    const int tid  = threadIdx.x;
    const int wave = tid >> 6;
    const int par  = tid & 1;

    // vectorized zero: 4800 words = 1200 uint4
    uint4* z = (uint4*)lh;
    for (int k = tid; k < 3*NW*2*TOTAL/4; k += BLK) z[k] = make_uint4(0,0,0,0);
    __syncthreads();

    const int gBeg = (int)(((long long)blockIdx.x       * Ttot) / GRID);
    const int gEnd = (int)(((long long)(blockIdx.x + 1) * Ttot) / GRID);

    for (int g = gBeg; g < gEnd; ++g) {
        // ---- decode tile id -> (type, rb, cb); all wave-uniform scalar math
        int type, rb, cb;
        if (g < T0) {
            type = 0; rb = 0;
            // offset(r) = cb0*r - (RATIO/2)*r*(r-1)
            while (rb + 1 < rows0 && (cb0*(rb+1) - (RATIO/2)*(rb+1)*rb) <= g) ++rb;
            cb = RATIO*rb + (g - (cb0*rb - (RATIO/2)*rb*(rb-1)));
        } else if (g < T01) {
            int u = g - T0; type = 1; rb = u / cb1; cb = u - rb*cb1;
        } else {
            int u = g - T01; type = 2; rb = 0;
            while (rb + 1 < rows1 && (cb1*(rb+1) - (RATIO/2)*(rb+1)*rb) <= u) ++rb;
            cb = RATIO*rb + (u - (cb1*rb - (RATIO/2)*rb*(rb-1)));
        }
        const float4* Ab = (type == 2) ? b1 : b0;
        const float4* Bb = (type == 0) ? b0 : b1;
        const int nA     = (type == 2) ? n1 : n0;

        const int rowBase = rb * BLK;
        const int colBase = cb * TB;
        const int aIdx    = rowBase + tid;

        float4 a = (aIdx < nA) ? Ab[aIdx]
                               : make_float4(0.f, 0.f, 0.f, 3.0e18f); // pad row -> no bins
        float4 bp = Bb[colBase + (tid & (TB - 1))];  // lane-private B point
        unsigned int* mylh = &lh[type][wave][par][0];

        const bool diag = (type != 1) && (colBase < rowBase + BLK); // straddles diagonal
        if (diag) pair_loop<true >(bp, a.x, a.y, a.z, a.w, mylh, aIdx - colBase);
        else      pair_loop<false>(bp, a.x, a.y, a.z, a.w, mylh, 0);
    }
    __syncthreads();

    // one flush per block to its replica; self-pair hists doubled (triangle)
    unsigned int* gh = ghist + (blockIdx.x & (NR - 1)) * (3 * TOTAL);
    for (int k = tid; k < 3 * TOTAL; k += BLK) {
        int type = k / TOTAL, bin = k - type * TOTAL;
        unsigned int c = 0;
        #pragma unroll
        for (int w = 0; w < NW; ++w)
            { c += lh[type][w][0][bin] + lh[type][w][1][bin]; }
        if (c) atomicAdd(&gh[k], (type == 1) ? c : 2u * c);
    }
}

// ---------------------------------------------------------------------------
// normalize: out[i][j][k] = count[i][j][k] + h_ij[k]/density/SLICE_VOL[k]/Na
// (verbatim from the verified round-0 kernel)
// ---------------------------------------------------------------------------
__global__ void rdf_final(const unsigned int* __restrict__ ghist,
                          const float* __restrict__ count,
                          const float* __restrict__ rs,
                          float* __restrict__ out, int n0, int n1)
{
    int t = blockIdx.x * blockDim.x + threadIdx.x;
    if (t >= 2*2*TOTAL) return;
    int k = t % TOTAL;
    int j = (t / TOTAL) & 1;
    int i = t / (2*TOTAL);

    float vol = rs[0]*rs[1]*rs[2];
    int Na = (i == 0) ? n0 : n1;
    int Nb = (j == 0) ? n0 : n1;
    int hidx = (i == j) ? (i == 0 ? 0 : 2) : 1;

    unsigned int c = 0;
    #pragma unroll
    for (int r = 0; r < NR; ++r) c += ghist[r*3*TOTAL + hidx*TOTAL + k];

    double sv  = ((0.025 + (double)k * 0.05) * 0.05) * 2.0 * M_PI * 3.0; // fp64 SLICE_VOL
    float  svf = (float)sv;
    float  density = (float)Nb / vol;
    float  r = (((float)c / density) / svf) / (float)Na;
    out[t] = count[t] + r;
}

extern "C" void kernel_launch(void* const* d_in, const int* in_sizes, int n_in,
                              void* d_out, int out_size, void* d_ws, size_t ws_size,
                              hipStream_t stream) {
    const float* pos0  = (const float*)d_in[0];
    const float* pos1  = (const float*)d_in[1];
    const float* count = (const float*)d_in[2];
    const float* rs    = (const float*)d_in[3];
    float* out = (float*)d_out;

    int n0 = in_sizes[0] / 3;   // 4096
    int n1 = in_sizes[1] / 3;   // 8192

    // ws layout: [ghist NR*3*200 u32 = 38.4KB][pad to 40KB][b0][b1]
    unsigned int* ghist = (unsigned int*)d_ws;
    float4* b0 = (float4*)((char*)d_ws + 40960);
    float4* b1 = b0 + n0;

    int prepBlocks = (n0 + n1 + BLK - 1) / BLK;   // 12288 threads >= 9600 hist words
    rdf_prep<<<prepBlocks, BLK, 0, stream>>>(pos0, pos1, rs, b0, b1, ghist, n0, n1);

    int rows0 = (n0 + BLK - 1) / BLK;   // 16
    int rows1 = (n1 + BLK - 1) / BLK;   // 32
    int cb0   = (n0 + TB - 1) / TB;     // 128
    int cb1   = (n1 + TB - 1) / TB;     // 256
    // triangle tile counts: sum_r (cols - RATIO*r) = cols*rows - (RATIO/2)*rows*(rows-1)
    int T0   = cb0*rows0 - (RATIO/2)*rows0*(rows0-1);   // 1088
    int Tc   = rows0*cb1;                               // 4096
    int T2   = cb1*rows1 - (RATIO/2)*rows1*(rows1-1);   // 4224
    int T01  = T0 + Tc;
    int Ttot = T01 + T2;                                // 9408

    rdf_hist<<<GRID, BLK, 0, stream>>>(b0, b1, ghist, n0, n1,
                                       T0, T01, Ttot, cb0, cb1, rows0, rows1);

    rdf_final<<<(2*2*TOTAL + BLK - 1) / BLK, BLK, 0, stream>>>(ghist, count, rs, out, n0, n1);
}